// Round 6
// baseline (465.751 us; speedup 1.0000x reference)
//
#include <hip/hip_runtime.h>
#include <math.h>

// R6: gene-bucketed two-phase. dot(u*v, w) == dot(u, v*w): bucket edges by
// gene (hist -> scan -> atomic scatter into perm/srcs), then one block per
// gene computes t_m = v_g*w_m once in registers and gathers ONLY the u row
// (256 B f16, table 2.56 MB = L2-resident) per edge. 8-edge macro with
// transpose-reduce + full-wave epilogue as in R5. Fallbacks: R5 edge kernel
// (ws >= 3 MB), pure f32 (tiny ws).

typedef _Float16 h2 __attribute__((ext_vector_type(2)));
union U16 { uint4 u; h2 h[4]; };
union HU { uint u; h2 h; };

// ---------------- utility kernels -------------------------------------------
__global__ void zero_kernel(int* __restrict__ p, int n) {
    int i = blockIdx.x * blockDim.x + threadIdx.x;
    if (i < n) p[i] = 0;
}

__global__ __launch_bounds__(256) void cvt_f16_kernel(
    const float4* __restrict__ src, uint2* __restrict__ dst, int n4)
{
    int i = blockIdx.x * blockDim.x + threadIdx.x;
    if (i >= n4) return;
    float4 f = src[i];
    HU a, b;
    a.h = h2{(_Float16)f.x, (_Float16)f.y};
    b.h = h2{(_Float16)f.z, (_Float16)f.w};
    dst[i] = make_uint2(a.u, b.u);
}

__global__ __launch_bounds__(256) void cvt_f16_fused_kernel(
    const float4* __restrict__ srcA, int nA4,
    const float4* __restrict__ srcB, int nB4,
    uint2* __restrict__ dst)
{
    int i = blockIdx.x * blockDim.x + threadIdx.x;
    if (i >= nA4 + nB4) return;
    float4 f = (i < nA4) ? srcA[i] : srcB[i - nA4];
    HU a, b;
    a.h = h2{(_Float16)f.x, (_Float16)f.y};
    b.h = h2{(_Float16)f.z, (_Float16)f.w};
    dst[i] = make_uint2(a.u, b.u);
}

// ---------------- sort phases ------------------------------------------------
__global__ __launch_bounds__(256) void hist_kernel(
    const int* __restrict__ dst_idx, int E, int n_genes, int* __restrict__ counts)
{
    __shared__ int h[2048];
    for (int i = threadIdx.x; i < 2048; i += 256) h[i] = 0;
    __syncthreads();
    const int stride = gridDim.x * blockDim.x;
    for (int e = blockIdx.x * blockDim.x + threadIdx.x; e < E; e += stride)
        atomicAdd(&h[dst_idx[e]], 1);
    __syncthreads();
    for (int i = threadIdx.x; i < n_genes; i += 256)
        if (h[i]) atomicAdd(&counts[i], h[i]);
}

// single block, 256 threads, 8 bins/thread (n_genes <= 2047)
__global__ __launch_bounds__(256) void scan_kernel(
    const int* __restrict__ counts, int n_genes,
    int* __restrict__ offsets, int* __restrict__ cursor)
{
    __shared__ int tot[256];
    const int t = threadIdx.x;
    const int base = t * 8;
    int local[8];
    int sum = 0;
#pragma unroll
    for (int i = 0; i < 8; ++i) {
        int k = base + i;
        int c = (k < n_genes) ? counts[k] : 0;
        local[i] = c; sum += c;
    }
    tot[t] = sum;
    __syncthreads();
    for (int o = 1; o < 256; o <<= 1) {
        int v = (t >= o) ? tot[t - o] : 0;
        __syncthreads();
        tot[t] += v;
        __syncthreads();
    }
    int run = tot[t] - sum;  // exclusive prefix of this thread's chunk
#pragma unroll
    for (int i = 0; i < 8; ++i) {
        int k = base + i;
        if (k <= n_genes) offsets[k] = run;
        if (k < n_genes) { cursor[k] = run; run += local[i]; }
    }
}

__global__ __launch_bounds__(256) void scatter_kernel(
    const int* __restrict__ src_idx, const int* __restrict__ dst_idx, int E,
    int* __restrict__ cursor, int* __restrict__ perm, int* __restrict__ srcs)
{
    const int stride = gridDim.x * blockDim.x;
    for (int e = blockIdx.x * blockDim.x + threadIdx.x; e < E; e += stride) {
        int g = dst_idx[e];
        int pos = atomicAdd(&cursor[g], 1);
        perm[pos] = e;
        srcs[pos] = src_idx[e];
    }
}

// ---------------- shared helpers --------------------------------------------
__device__ __forceinline__ float reduce8t(
    float x0, float x1, float x2, float x3,
    float x4, float x5, float x6, float x7, int r)
{
    const bool h1 = (r & 1), h2b = (r & 2), h4 = (r & 4);
    float b0 = (h1 ? x1 : x0) + __shfl_xor(h1 ? x0 : x1, 1, 8);
    float b1 = (h1 ? x3 : x2) + __shfl_xor(h1 ? x2 : x3, 1, 8);
    float b2 = (h1 ? x5 : x4) + __shfl_xor(h1 ? x4 : x5, 1, 8);
    float b3 = (h1 ? x7 : x6) + __shfl_xor(h1 ? x6 : x7, 1, 8);
    float c0 = (h2b ? b1 : b0) + __shfl_xor(h2b ? b0 : b1, 2, 8);
    float c1 = (h2b ? b3 : b2) + __shfl_xor(h2b ? b2 : b3, 2, 8);
    return (h4 ? c1 : c0) + __shfl_xor(h4 ? c0 : c1, 4, 8);
}

// 24 fdot2: one edge's 16 elems held by this lane, against t (= v*w) slices.
__device__ __forceinline__ void dotu(
    const U16& ua, const U16& ub,
    const h2* tm, const h2* td, const h2* tp,
    float& m, float& dd, float& pp)
{
#pragma unroll
    for (int jj = 0; jj < 4; ++jj) {
        m  = __builtin_amdgcn_fdot2(ua.h[jj], tm[jj], m,  false);
        dd = __builtin_amdgcn_fdot2(ua.h[jj], td[jj], dd, false);
        pp = __builtin_amdgcn_fdot2(ua.h[jj], tp[jj], pp, false);
        m  = __builtin_amdgcn_fdot2(ub.h[jj], tm[4 + jj], m,  false);
        dd = __builtin_amdgcn_fdot2(ub.h[jj], td[4 + jj], dd, false);
        pp = __builtin_amdgcn_fdot2(ub.h[jj], tp[4 + jj], pp, false);
    }
}

#define LOADU(J, SJ)                                                     \
    const uint4* uP##J = (const uint4*)(uhalf + (size_t)(SJ) * 128);     \
    U16 uA##J, uB##J;                                                    \
    uA##J.u = uP##J[r]; uB##J.u = uP##J[r + 8];

// ---------------- bucketed main kernel: one block per gene -------------------
__global__ __launch_bounds__(256, 2) void zinb_bucket_kernel(
    const _Float16* __restrict__ uhalf,   // [n_cells, 128] f16
    const float* __restrict__ ifeats,     // [n_genes, 128] f32
    const float* __restrict__ ge_factor,
    const float* __restrict__ sz_factor,
    const float* __restrict__ W_mean, const float* __restrict__ b_mean,
    const float* __restrict__ W_disp, const float* __restrict__ b_disp,
    const float* __restrict__ W_pi,   const float* __restrict__ b_pi,
    const int* __restrict__ offsets,
    const int* __restrict__ perm,
    const int* __restrict__ srcs,
    float* __restrict__ out, int E, int n_genes)
{
    const int g = blockIdx.x;
    if (g >= n_genes) return;
    const int off = offsets[g];
    const int cnt = offsets[g + 1] - off;
    if (cnt == 0) return;

    const int tid = threadIdx.x;
    const int r = tid & 7;
    const int gid = tid >> 3;          // 0..31 groups per block
    const float gef = ge_factor[g];

    // t_m = v_g * w_m, f16 pairs; lane r owns elems c*64 + r*8 + [0,8)
    h2 tm[8], td[8], tp[8];
    const float* vrow = ifeats + (size_t)g * 128;
#pragma unroll
    for (int c = 0; c < 2; ++c)
#pragma unroll
        for (int j = 0; j < 4; ++j) {
            int k = c * 64 + r * 8 + 2 * j;
            float v0 = vrow[k], v1 = vrow[k + 1];
            tm[c * 4 + j] = h2{(_Float16)(v0 * W_mean[k]), (_Float16)(v1 * W_mean[k + 1])};
            td[c * 4 + j] = h2{(_Float16)(v0 * W_disp[k]), (_Float16)(v1 * W_disp[k + 1])};
            tp[c * 4 + j] = h2{(_Float16)(v0 * W_pi[k]),   (_Float16)(v1 * W_pi[k + 1])};
        }
    const float bm = b_mean[0], bd = b_disp[0], bp = b_pi[0];

    const int full_m = cnt >> 3;
    for (int m = gid; m < full_m; m += 32) {
        const int base = off + m * 8;
        const int se  = srcs[base + r];   // src of this lane's edge
        const int e_r = perm[base + r];   // original edge id of this lane's edge
        const float szf = sz_factor[se];

        const int s0 = __shfl(se, 0, 8), s1 = __shfl(se, 1, 8);
        const int s2 = __shfl(se, 2, 8), s3 = __shfl(se, 3, 8);
        const int s4 = __shfl(se, 4, 8), s5 = __shfl(se, 5, 8);
        const int s6 = __shfl(se, 6, 8), s7 = __shfl(se, 7, 8);

        LOADU(0, s0) LOADU(1, s1) LOADU(2, s2) LOADU(3, s3)
        LOADU(4, s4) LOADU(5, s5) LOADU(6, s6) LOADU(7, s7)

        float m0 = 0.f, d0 = 0.f, p0 = 0.f; dotu(uA0, uB0, tm, td, tp, m0, d0, p0);
        float m1 = 0.f, d1 = 0.f, p1 = 0.f; dotu(uA1, uB1, tm, td, tp, m1, d1, p1);
        float m2 = 0.f, d2 = 0.f, p2 = 0.f; dotu(uA2, uB2, tm, td, tp, m2, d2, p2);
        float m3 = 0.f, d3 = 0.f, p3 = 0.f; dotu(uA3, uB3, tm, td, tp, m3, d3, p3);
        float m4 = 0.f, d4 = 0.f, p4 = 0.f; dotu(uA4, uB4, tm, td, tp, m4, d4, p4);
        float m5 = 0.f, d5 = 0.f, p5 = 0.f; dotu(uA5, uB5, tm, td, tp, m5, d5, p5);
        float m6 = 0.f, d6 = 0.f, p6 = 0.f; dotu(uA6, uB6, tm, td, tp, m6, d6, p6);
        float m7 = 0.f, d7 = 0.f, p7 = 0.f; dotu(uA7, uB7, tm, td, tp, m7, d7, p7);

        const float rm = reduce8t(m0, m1, m2, m3, m4, m5, m6, m7, r);
        const float rd = reduce8t(d0, d1, d2, d3, d4, d5, d6, d7, r);
        const float rp = reduce8t(p0, p1, p2, p3, p4, p5, p6, p7, r);

        const float mu_ = 1.f / (1.f + __expf(-(rm + bm)));
        const float pi  = 1.f / (1.f + __expf(-(rp + bp)));
        const float xd  = gef * (rd + bd);
        const float sp  = fmaxf(xd, 0.f) + __logf(1.f + __expf(-fabsf(xd)));
        const float disp = fminf(fmaxf(sp, 1e-4f), 1e4f);
        const float mu = szf * fminf(fmaxf(__expf(gef * mu_) - 1.f, 1e-5f), 1e6f);

        out[e_r]                 = mu;
        out[(size_t)E + e_r]     = disp;
        out[(size_t)2 * E + e_r] = pi;
    }

    // bucket tail: cnt & 7 edges, one group each
    const int tcnt = cnt & 7;
    if (gid < tcnt) {
        const int pos = off + full_m * 8 + gid;
        const int s = srcs[pos];
        const int e = perm[pos];
        LOADU(T, s)
        float am = 0.f, ad = 0.f, ap = 0.f;
        dotu(uAT, uBT, tm, td, tp, am, ad, ap);
#pragma unroll
        for (int o = 1; o < 8; o <<= 1) {
            am += __shfl_xor(am, o, 8); ad += __shfl_xor(ad, o, 8); ap += __shfl_xor(ap, o, 8);
        }
        if (r == 0) {
            const float szf = sz_factor[s];
            const float mu_ = 1.f / (1.f + __expf(-(am + bm)));
            const float pi  = 1.f / (1.f + __expf(-(ap + bp)));
            const float xd  = gef * (ad + bd);
            const float sp  = fmaxf(xd, 0.f) + __logf(1.f + __expf(-fabsf(xd)));
            const float disp = fminf(fmaxf(sp, 1e-4f), 1e4f);
            const float mu = szf * fminf(fmaxf(__expf(gef * mu_) - 1.f, 1e-5f), 1e6f);
            out[e] = mu; out[(size_t)E + e] = disp; out[(size_t)2 * E + e] = pi;
        }
    }
}

// ---------------- R5 fallback: 8-edge macro edge-order kernel ----------------
__device__ __forceinline__ void dot3(
    const U16& ua, const U16& ub, const U16& va, const U16& vb,
    const h2* wm, const h2* wd, const h2* wp,
    float& m, float& dd, float& pp)
{
#pragma unroll
    for (int jj = 0; jj < 4; ++jj) {
        h2 p0 = ua.h[jj] * va.h[jj];
        m  = __builtin_amdgcn_fdot2(p0, wm[jj], m,  false);
        dd = __builtin_amdgcn_fdot2(p0, wd[jj], dd, false);
        pp = __builtin_amdgcn_fdot2(p0, wp[jj], pp, false);
        h2 p1 = ub.h[jj] * vb.h[jj];
        m  = __builtin_amdgcn_fdot2(p1, wm[4 + jj], m,  false);
        dd = __builtin_amdgcn_fdot2(p1, wd[4 + jj], dd, false);
        pp = __builtin_amdgcn_fdot2(p1, wp[4 + jj], pp, false);
    }
}

#define LOADE(J, SJ, GJ)                                                  \
    const uint4* uP##J = (const uint4*)(uhalf + (size_t)(SJ) * 128);      \
    const uint4* vP##J = (const uint4*)(ihalf + (size_t)(GJ) * 128);      \
    U16 uA##J, uB##J, vA##J, vB##J;                                       \
    uA##J.u = uP##J[r]; uB##J.u = uP##J[r + 8];                           \
    vA##J.u = vP##J[r]; vB##J.u = vP##J[r + 8];

__global__ __launch_bounds__(256, 2) void zinb_edge8_kernel(
    const _Float16* __restrict__ uhalf, const _Float16* __restrict__ ihalf,
    const float* __restrict__ ge_factor, const float* __restrict__ sz_factor,
    const float* __restrict__ W_mean, const float* __restrict__ b_mean,
    const float* __restrict__ W_disp, const float* __restrict__ b_disp,
    const float* __restrict__ W_pi,   const float* __restrict__ b_pi,
    const int* __restrict__ src_idx, const int* __restrict__ dst_idx,
    float* __restrict__ out, int E)
{
    const int tid = threadIdx.x;
    const int r = tid & 7;
    const int slot = (blockIdx.x * blockDim.x + tid) >> 3;
    const int n_slots = (gridDim.x * blockDim.x) >> 3;

    h2 wm[8], wd[8], wp[8];
#pragma unroll
    for (int c = 0; c < 2; ++c)
#pragma unroll
        for (int j = 0; j < 4; ++j) {
            int k = c * 64 + r * 8 + 2 * j;
            wm[c * 4 + j] = h2{(_Float16)W_mean[k], (_Float16)W_mean[k + 1]};
            wd[c * 4 + j] = h2{(_Float16)W_disp[k], (_Float16)W_disp[k + 1]};
            wp[c * 4 + j] = h2{(_Float16)W_pi[k],   (_Float16)W_pi[k + 1]};
        }
    const float bm = b_mean[0], bd = b_disp[0], bp = b_pi[0];

    const int nmac = E >> 3;
    const int4* src4 = (const int4*)src_idx;
    const int4* dst4 = (const int4*)dst_idx;

    for (int q = slot; q < nmac; q += n_slots) {
        const int e0 = q << 3;
        const int4 s03 = src4[2 * q];
        const int4 s47 = src4[2 * q + 1];
        const int4 g03 = dst4[2 * q];
        const int4 g47 = dst4[2 * q + 1];
        const int  se  = src_idx[e0 + r];
        const int  de  = dst_idx[e0 + r];
        const float szf = sz_factor[se];
        const float gef = ge_factor[de];

        LOADE(0, s03.x, g03.x) LOADE(1, s03.y, g03.y)
        LOADE(2, s03.z, g03.z) LOADE(3, s03.w, g03.w)
        LOADE(4, s47.x, g47.x) LOADE(5, s47.y, g47.y)
        LOADE(6, s47.z, g47.z) LOADE(7, s47.w, g47.w)

        float m0 = 0.f, d0 = 0.f, p0 = 0.f; dot3(uA0, uB0, vA0, vB0, wm, wd, wp, m0, d0, p0);
        float m1 = 0.f, d1 = 0.f, p1 = 0.f; dot3(uA1, uB1, vA1, vB1, wm, wd, wp, m1, d1, p1);
        float m2 = 0.f, d2 = 0.f, p2 = 0.f; dot3(uA2, uB2, vA2, vB2, wm, wd, wp, m2, d2, p2);
        float m3 = 0.f, d3 = 0.f, p3 = 0.f; dot3(uA3, uB3, vA3, vB3, wm, wd, wp, m3, d3, p3);
        float m4 = 0.f, d4 = 0.f, p4 = 0.f; dot3(uA4, uB4, vA4, vB4, wm, wd, wp, m4, d4, p4);
        float m5 = 0.f, d5 = 0.f, p5 = 0.f; dot3(uA5, uB5, vA5, vB5, wm, wd, wp, m5, d5, p5);
        float m6 = 0.f, d6 = 0.f, p6 = 0.f; dot3(uA6, uB6, vA6, vB6, wm, wd, wp, m6, d6, p6);
        float m7 = 0.f, d7 = 0.f, p7 = 0.f; dot3(uA7, uB7, vA7, vB7, wm, wd, wp, m7, d7, p7);

        const float rm = reduce8t(m0, m1, m2, m3, m4, m5, m6, m7, r);
        const float rd = reduce8t(d0, d1, d2, d3, d4, d5, d6, d7, r);
        const float rp = reduce8t(p0, p1, p2, p3, p4, p5, p6, p7, r);

        const float mu_ = 1.f / (1.f + __expf(-(rm + bm)));
        const float pi  = 1.f / (1.f + __expf(-(rp + bp)));
        const float xd  = gef * (rd + bd);
        const float sp  = fmaxf(xd, 0.f) + __logf(1.f + __expf(-fabsf(xd)));
        const float disp = fminf(fmaxf(sp, 1e-4f), 1e4f);
        const float mu = szf * fminf(fmaxf(__expf(gef * mu_) - 1.f, 1e-5f), 1e6f);

        const int e = e0 + r;
        out[e]                 = mu;
        out[(size_t)E + e]     = disp;
        out[(size_t)2 * E + e] = pi;
    }
}

__global__ void zinb_tail_kernel(
    const float* __restrict__ ufeats, const float* __restrict__ ifeats,
    const float* __restrict__ ge_factor, const float* __restrict__ sz_factor,
    const float* __restrict__ W_mean, const float* __restrict__ b_mean,
    const float* __restrict__ W_disp, const float* __restrict__ b_disp,
    const float* __restrict__ W_pi,   const float* __restrict__ b_pi,
    const int* __restrict__ src_idx, const int* __restrict__ dst_idx,
    float* __restrict__ out, int E, int start)
{
    int e = start + blockIdx.x * blockDim.x + threadIdx.x;
    if (e >= E) return;
    const int s = src_idx[e], g = dst_idx[e];
    float am = 0.f, ad = 0.f, ap = 0.f;
    for (int k = 0; k < 128; ++k) {
        float h = ufeats[(size_t)s * 128 + k] * ifeats[(size_t)g * 128 + k];
        am = fmaf(h, W_mean[k], am);
        ad = fmaf(h, W_disp[k], ad);
        ap = fmaf(h, W_pi[k],   ap);
    }
    const float gef = ge_factor[g];
    const float szf = sz_factor[s];
    const float mu_ = 1.f / (1.f + __expf(-(am + b_mean[0])));
    const float pi  = 1.f / (1.f + __expf(-(ap + b_pi[0])));
    const float xd  = gef * (ad + b_disp[0]);
    const float sp  = fmaxf(xd, 0.f) + __logf(1.f + __expf(-fabsf(xd)));
    const float disp = fminf(fmaxf(sp, 1e-4f), 1e4f);
    const float mu = szf * fminf(fmaxf(__expf(gef * mu_) - 1.f, 1e-5f), 1e6f);
    out[e] = mu; out[(size_t)E + e] = disp; out[(size_t)2 * E + e] = pi;
}

__global__ __launch_bounds__(256) void zinb_edge_f32_kernel(
    const float* __restrict__ ufeats, const float* __restrict__ ifeats,
    const float* __restrict__ ge_factor, const float* __restrict__ sz_factor,
    const float* __restrict__ W_mean, const float* __restrict__ b_mean,
    const float* __restrict__ W_disp, const float* __restrict__ b_disp,
    const float* __restrict__ W_pi,   const float* __restrict__ b_pi,
    const int* __restrict__ src_idx, const int* __restrict__ dst_idx,
    float* __restrict__ out, int E)
{
    const int r = threadIdx.x & 7;
    const int slot = (blockIdx.x * blockDim.x + threadIdx.x) >> 3;
    const int n_slots = (gridDim.x * blockDim.x) >> 3;

    float4 wm[4], wd[4], wp[4];
    {
        const float4* wm4 = (const float4*)W_mean + r;
        const float4* wd4 = (const float4*)W_disp + r;
        const float4* wp4 = (const float4*)W_pi   + r;
#pragma unroll
        for (int c = 0; c < 4; ++c) { wm[c] = wm4[c*8]; wd[c] = wd4[c*8]; wp[c] = wp4[c*8]; }
    }
    const float bm = b_mean[0], bd = b_disp[0], bp = b_pi[0];

    for (int e = slot; e < E; e += n_slots) {
        const int s = src_idx[e];
        const int g = dst_idx[e];
        const float4* u4 = (const float4*)(ufeats + (size_t)s * 128) + r;
        const float4* v4 = (const float4*)(ifeats + (size_t)g * 128) + r;
        float am = 0.f, ad = 0.f, ap = 0.f;
#pragma unroll
        for (int c = 0; c < 4; ++c) {
            float4 u = u4[c*8]; float4 v = v4[c*8];
            float px = u.x*v.x, py = u.y*v.y, pz = u.z*v.z, pw = u.w*v.w;
            am = fmaf(px, wm[c].x, am); am = fmaf(py, wm[c].y, am);
            am = fmaf(pz, wm[c].z, am); am = fmaf(pw, wm[c].w, am);
            ad = fmaf(px, wd[c].x, ad); ad = fmaf(py, wd[c].y, ad);
            ad = fmaf(pz, wd[c].z, ad); ad = fmaf(pw, wd[c].w, ad);
            ap = fmaf(px, wp[c].x, ap); ap = fmaf(py, wp[c].y, ap);
            ap = fmaf(pz, wp[c].z, ap); ap = fmaf(pw, wp[c].w, ap);
        }
#pragma unroll
        for (int off = 1; off < 8; off <<= 1) {
            am += __shfl_xor(am, off); ad += __shfl_xor(ad, off); ap += __shfl_xor(ap, off);
        }
        if (r == 0) {
            const float gef = ge_factor[g];
            const float szf = sz_factor[s];
            const float mu_ = 1.f / (1.f + __expf(-(am + bm)));
            const float pi  = 1.f / (1.f + __expf(-(ap + bp)));
            const float xd  = gef * (ad + bd);
            const float sp  = fmaxf(xd, 0.f) + __logf(1.f + __expf(-fabsf(xd)));
            const float disp = fminf(fmaxf(sp, 1e-4f), 1e4f);
            const float mu = szf * fminf(fmaxf(__expf(gef * mu_) - 1.f, 1e-5f), 1e6f);
            out[e] = mu; out[(size_t)E + e] = disp; out[(size_t)2*E + e] = pi;
        }
    }
}

// ---------------- launcher ---------------------------------------------------
static inline size_t align256(size_t x) { return (x + 255) & ~(size_t)255; }

extern "C" void kernel_launch(void* const* d_in, const int* in_sizes, int n_in,
                              void* d_out, int out_size, void* d_ws, size_t ws_size,
                              hipStream_t stream) {
    const float* ufeats    = (const float*)d_in[0];
    const float* ifeats    = (const float*)d_in[1];
    const float* ge_factor = (const float*)d_in[2];
    const float* sz_factor = (const float*)d_in[3];
    const float* W_mean    = (const float*)d_in[4];
    const float* b_mean    = (const float*)d_in[5];
    const float* W_disp    = (const float*)d_in[6];
    const float* b_disp    = (const float*)d_in[7];
    const float* W_pi      = (const float*)d_in[8];
    const float* b_pi      = (const float*)d_in[9];
    const int*   src_idx   = (const int*)d_in[10];
    const int*   dst_idx   = (const int*)d_in[11];
    float* out = (float*)d_out;

    const int E       = in_sizes[10];
    const int n_cells = in_sizes[0] / 128;
    const int n_genes = in_sizes[1] / 128;

    const size_t u_elems = (size_t)n_cells * 128;
    const size_t i_elems = (size_t)n_genes * 128;

    // ws layout for bucketed path
    const size_t uhalf_b   = align256(u_elems * sizeof(_Float16));
    const size_t counts_b  = align256((size_t)(n_genes + 1) * sizeof(int));
    const size_t offsets_b = align256((size_t)(n_genes + 1) * sizeof(int));
    const size_t cursor_b  = align256((size_t)n_genes * sizeof(int));
    const size_t perm_b    = align256((size_t)E * sizeof(int));
    const size_t srcs_b    = align256((size_t)E * sizeof(int));
    const size_t bucket_need = uhalf_b + counts_b + offsets_b + cursor_b + perm_b + srcs_b;

    if (ws_size >= bucket_need && n_genes >= 1 && n_genes <= 2047) {
        char* p = (char*)d_ws;
        _Float16* uhalf = (_Float16*)p;          p += uhalf_b;
        int* counts  = (int*)p;                  p += counts_b;
        int* offsets = (int*)p;                  p += offsets_b;
        int* cursor  = (int*)p;                  p += cursor_b;
        int* perm    = (int*)p;                  p += perm_b;
        int* srcs    = (int*)p;                  p += srcs_b;

        const int ncounts = n_genes + 1;
        hipLaunchKernelGGL(zero_kernel, dim3((ncounts + 255) / 256), dim3(256), 0, stream,
                           counts, ncounts);
        hipLaunchKernelGGL(hist_kernel, dim3(128), dim3(256), 0, stream,
                           dst_idx, E, n_genes, counts);
        hipLaunchKernelGGL(scan_kernel, dim3(1), dim3(256), 0, stream,
                           counts, n_genes, offsets, cursor);
        hipLaunchKernelGGL(scatter_kernel, dim3(512), dim3(256), 0, stream,
                           src_idx, dst_idx, E, cursor, perm, srcs);
        const int un4 = (int)(u_elems / 4);
        hipLaunchKernelGGL(cvt_f16_kernel, dim3((un4 + 255) / 256), dim3(256), 0, stream,
                           (const float4*)ufeats, (uint2*)uhalf, un4);
        hipLaunchKernelGGL(zinb_bucket_kernel, dim3(n_genes), dim3(256), 0, stream,
                           uhalf, ifeats, ge_factor, sz_factor,
                           W_mean, b_mean, W_disp, b_disp, W_pi, b_pi,
                           offsets, perm, srcs, out, E, n_genes);
        return;
    }

    const size_t r5_need = (u_elems + i_elems) * sizeof(_Float16);
    if (ws_size >= r5_need) {
        _Float16* uhalf = (_Float16*)d_ws;
        _Float16* ihalf = uhalf + u_elems;
        const int un4 = (int)(u_elems / 4);
        const int in4 = (int)(i_elems / 4);
        hipLaunchKernelGGL(cvt_f16_fused_kernel, dim3((un4 + in4 + 255) / 256), dim3(256), 0, stream,
                           (const float4*)ufeats, un4, (const float4*)ifeats, in4,
                           (uint2*)d_ws);
        hipLaunchKernelGGL(zinb_edge8_kernel, dim3(2048), dim3(256), 0, stream,
                           uhalf, ihalf, ge_factor, sz_factor,
                           W_mean, b_mean, W_disp, b_disp, W_pi, b_pi,
                           src_idx, dst_idx, out, E);
        const int rem = E & 7;
        if (rem) {
            hipLaunchKernelGGL(zinb_tail_kernel, dim3(1), dim3(64), 0, stream,
                               ufeats, ifeats, ge_factor, sz_factor,
                               W_mean, b_mean, W_disp, b_disp, W_pi, b_pi,
                               src_idx, dst_idx, out, E, E - rem);
        }
    } else {
        hipLaunchKernelGGL(zinb_edge_f32_kernel, dim3(2048), dim3(256), 0, stream,
                           ufeats, ifeats, ge_factor, sz_factor,
                           W_mean, b_mean, W_disp, b_disp, W_pi, b_pi,
                           src_idx, dst_idx, out, E);
    }
}

// Round 7
// 145.068 us; speedup vs baseline: 3.2106x; 3.2106x over previous
//
#include <hip/hip_runtime.h>
#include <math.h>

// R7: R5 structure (f16 tables in ws, 8 lanes/edge, 8-edge macro, transpose-
// reduce, full-wave epilogue) + software-pipelined idx loads: next macro-
// iteration's 4 int4 idx loads are issued during current compute, hiding the
// ~900-cyc HBM latency that headed R5's dependent chain. Per-lane own-edge
// idx derived from int4 regs via select (removes 2 dependent vmem ops).
// R6's atomic-scatter bucketing abandoned: 2M atomics over 2000 cursors
// serialized (248 us, VALUBusy 0.2%).

typedef _Float16 h2 __attribute__((ext_vector_type(2)));
union U16 { uint4 u; h2 h[4]; };
union HU { uint u; h2 h; };

// ---------- fused conversion kernel: both tables f32 -> f16 ------------------
__global__ __launch_bounds__(256) void cvt_f16_fused_kernel(
    const float4* __restrict__ srcA, int nA4,
    const float4* __restrict__ srcB, int nB4,
    uint2* __restrict__ dst)
{
    int i = blockIdx.x * blockDim.x + threadIdx.x;
    if (i >= nA4 + nB4) return;
    float4 f = (i < nA4) ? srcA[i] : srcB[i - nA4];
    HU a, b;
    a.h = h2{(_Float16)f.x, (_Float16)f.y};
    b.h = h2{(_Float16)f.z, (_Float16)f.w};
    dst[i] = make_uint2(a.u, b.u);
}

// 8-lane recursive-halving transpose-reduce: x0..x7 are per-lane partials for
// edges e0..e0+7; returns the full 8-lane sum of edge e0+r on lane r.
__device__ __forceinline__ float reduce8t(
    float x0, float x1, float x2, float x3,
    float x4, float x5, float x6, float x7, int r)
{
    const bool h1 = (r & 1), h2b = (r & 2), h4 = (r & 4);
    float b0 = (h1 ? x1 : x0) + __shfl_xor(h1 ? x0 : x1, 1, 8);
    float b1 = (h1 ? x3 : x2) + __shfl_xor(h1 ? x2 : x3, 1, 8);
    float b2 = (h1 ? x5 : x4) + __shfl_xor(h1 ? x4 : x5, 1, 8);
    float b3 = (h1 ? x7 : x6) + __shfl_xor(h1 ? x6 : x7, 1, 8);
    float c0 = (h2b ? b1 : b0) + __shfl_xor(h2b ? b0 : b1, 2, 8);
    float c1 = (h2b ? b3 : b2) + __shfl_xor(h2b ? b2 : b3, 2, 8);
    return (h4 ? c1 : c0) + __shfl_xor(h4 ? c0 : c1, 4, 8);
}

// select component r (0..7) from the pair (a = elems 0..3, b = elems 4..7)
__device__ __forceinline__ int sel8(const int4& a, const int4& b, int r)
{
    const int4 c = (r & 4) ? b : a;
    return (r & 2) ? ((r & 1) ? c.w : c.z) : ((r & 1) ? c.y : c.x);
}

// 24 fdot2 for one edge's 64 elements held by this lane.
__device__ __forceinline__ void dot3(
    const U16& ua, const U16& ub, const U16& va, const U16& vb,
    const h2* wm, const h2* wd, const h2* wp,
    float& m, float& dd, float& pp)
{
#pragma unroll
    for (int jj = 0; jj < 4; ++jj) {
        h2 p0 = ua.h[jj] * va.h[jj];
        m  = __builtin_amdgcn_fdot2(p0, wm[jj], m,  false);
        dd = __builtin_amdgcn_fdot2(p0, wd[jj], dd, false);
        pp = __builtin_amdgcn_fdot2(p0, wp[jj], pp, false);
        h2 p1 = ub.h[jj] * vb.h[jj];
        m  = __builtin_amdgcn_fdot2(p1, wm[4 + jj], m,  false);
        dd = __builtin_amdgcn_fdot2(p1, wd[4 + jj], dd, false);
        pp = __builtin_amdgcn_fdot2(p1, wp[4 + jj], pp, false);
    }
}

#define LOADE(J, SJ, GJ)                                                  \
    const uint4* uP##J = (const uint4*)(uhalf + (size_t)(SJ) * 128);      \
    const uint4* vP##J = (const uint4*)(ihalf + (size_t)(GJ) * 128);      \
    U16 uA##J, uB##J, vA##J, vB##J;                                       \
    uA##J.u = uP##J[r]; uB##J.u = uP##J[r + 8];                           \
    vA##J.u = vP##J[r]; vB##J.u = vP##J[r + 8];

// ---------- main edge kernel -------------------------------------------------
__global__ __launch_bounds__(256, 2) void zinb_edge8p_kernel(
    const _Float16* __restrict__ uhalf,   // [n_cells, 128]
    const _Float16* __restrict__ ihalf,   // [n_genes, 128]
    const float* __restrict__ ge_factor,
    const float* __restrict__ sz_factor,
    const float* __restrict__ W_mean, const float* __restrict__ b_mean,
    const float* __restrict__ W_disp, const float* __restrict__ b_disp,
    const float* __restrict__ W_pi,   const float* __restrict__ b_pi,
    const int* __restrict__ src_idx,
    const int* __restrict__ dst_idx,
    float* __restrict__ out,              // [3E]: mu | disp | pi
    int E)
{
    const int tid = threadIdx.x;
    const int r = tid & 7;
    const int slot = (blockIdx.x * blockDim.x + tid) >> 3;
    const int n_slots = (gridDim.x * blockDim.x) >> 3;

    // W slices as f16 pairs: lane r owns elems [r*8, r*8+8) and [64+r*8, ...)
    h2 wm[8], wd[8], wp[8];
#pragma unroll
    for (int c = 0; c < 2; ++c)
#pragma unroll
        for (int j = 0; j < 4; ++j) {
            int k = c * 64 + r * 8 + 2 * j;
            wm[c * 4 + j] = h2{(_Float16)W_mean[k], (_Float16)W_mean[k + 1]};
            wd[c * 4 + j] = h2{(_Float16)W_disp[k], (_Float16)W_disp[k + 1]};
            wp[c * 4 + j] = h2{(_Float16)W_pi[k],   (_Float16)W_pi[k + 1]};
        }
    const float bm = b_mean[0], bd = b_disp[0], bp = b_pi[0];

    const int nmac = E >> 3;
    const int4* src4 = (const int4*)src_idx;
    const int4* dst4 = (const int4*)dst_idx;

    int q = slot;
    if (q >= nmac) return;

    // pre-load first iteration's indices
    int4 s03 = src4[2 * q], s47 = src4[2 * q + 1];
    int4 g03 = dst4[2 * q], g47 = dst4[2 * q + 1];

    while (q < nmac) {
        const int e0 = q << 3;
        const int nq = q + n_slots;

        // issue all 32 feature loads from already-resident idx registers
        LOADE(0, s03.x, g03.x)
        LOADE(1, s03.y, g03.y)
        LOADE(2, s03.z, g03.z)
        LOADE(3, s03.w, g03.w)
        LOADE(4, s47.x, g47.x)
        LOADE(5, s47.y, g47.y)
        LOADE(6, s47.z, g47.z)
        LOADE(7, s47.w, g47.w)

        // per-lane own-edge idx via register select (no extra vmem)
        const int se = sel8(s03, s47, r);
        const int de = sel8(g03, g47, r);
        const float szf = sz_factor[se];
        const float gef = ge_factor[de];

        // prefetch next iteration's indices (overlaps all compute below)
        if (nq < nmac) {
            s03 = src4[2 * nq]; s47 = src4[2 * nq + 1];
            g03 = dst4[2 * nq]; g47 = dst4[2 * nq + 1];
        }

        float m0 = 0.f, d0 = 0.f, p0 = 0.f; dot3(uA0, uB0, vA0, vB0, wm, wd, wp, m0, d0, p0);
        float m1 = 0.f, d1 = 0.f, p1 = 0.f; dot3(uA1, uB1, vA1, vB1, wm, wd, wp, m1, d1, p1);
        float m2 = 0.f, d2 = 0.f, p2 = 0.f; dot3(uA2, uB2, vA2, vB2, wm, wd, wp, m2, d2, p2);
        float m3 = 0.f, d3 = 0.f, p3 = 0.f; dot3(uA3, uB3, vA3, vB3, wm, wd, wp, m3, d3, p3);
        float m4 = 0.f, d4 = 0.f, p4 = 0.f; dot3(uA4, uB4, vA4, vB4, wm, wd, wp, m4, d4, p4);
        float m5 = 0.f, d5 = 0.f, p5 = 0.f; dot3(uA5, uB5, vA5, vB5, wm, wd, wp, m5, d5, p5);
        float m6 = 0.f, d6 = 0.f, p6 = 0.f; dot3(uA6, uB6, vA6, vB6, wm, wd, wp, m6, d6, p6);
        float m7 = 0.f, d7 = 0.f, p7 = 0.f; dot3(uA7, uB7, vA7, vB7, wm, wd, wp, m7, d7, p7);

        const float rm = reduce8t(m0, m1, m2, m3, m4, m5, m6, m7, r);
        const float rd = reduce8t(d0, d1, d2, d3, d4, d5, d6, d7, r);
        const float rp = reduce8t(p0, p1, p2, p3, p4, p5, p6, p7, r);

        // full-wave epilogue (each lane = one edge)
        const float mu_ = 1.f / (1.f + __expf(-(rm + bm)));
        const float pi  = 1.f / (1.f + __expf(-(rp + bp)));
        const float xd  = gef * (rd + bd);
        const float sp  = fmaxf(xd, 0.f) + __logf(1.f + __expf(-fabsf(xd)));
        const float disp = fminf(fmaxf(sp, 1e-4f), 1e4f);
        const float mu = szf * fminf(fmaxf(__expf(gef * mu_) - 1.f, 1e-5f), 1e6f);

        const int e = e0 + r;
        out[e]                 = mu;
        out[(size_t)E + e]     = disp;
        out[(size_t)2 * E + e] = pi;

        q = nq;
    }
}

// ---------- tail kernel: last E%8 edges, scalar f32 --------------------------
__global__ void zinb_tail_kernel(
    const float* __restrict__ ufeats, const float* __restrict__ ifeats,
    const float* __restrict__ ge_factor, const float* __restrict__ sz_factor,
    const float* __restrict__ W_mean, const float* __restrict__ b_mean,
    const float* __restrict__ W_disp, const float* __restrict__ b_disp,
    const float* __restrict__ W_pi,   const float* __restrict__ b_pi,
    const int* __restrict__ src_idx, const int* __restrict__ dst_idx,
    float* __restrict__ out, int E, int start)
{
    int e = start + blockIdx.x * blockDim.x + threadIdx.x;
    if (e >= E) return;
    const int s = src_idx[e], g = dst_idx[e];
    float am = 0.f, ad = 0.f, ap = 0.f;
    for (int k = 0; k < 128; ++k) {
        float h = ufeats[(size_t)s * 128 + k] * ifeats[(size_t)g * 128 + k];
        am = fmaf(h, W_mean[k], am);
        ad = fmaf(h, W_disp[k], ad);
        ap = fmaf(h, W_pi[k],   ap);
    }
    const float gef = ge_factor[g];
    const float szf = sz_factor[s];
    const float mu_ = 1.f / (1.f + __expf(-(am + b_mean[0])));
    const float pi  = 1.f / (1.f + __expf(-(ap + b_pi[0])));
    const float xd  = gef * (ad + b_disp[0]);
    const float sp  = fmaxf(xd, 0.f) + __logf(1.f + __expf(-fabsf(xd)));
    const float disp = fminf(fmaxf(sp, 1e-4f), 1e4f);
    const float mu = szf * fminf(fmaxf(__expf(gef * mu_) - 1.f, 1e-5f), 1e6f);
    out[e] = mu; out[(size_t)E + e] = disp; out[(size_t)2 * E + e] = pi;
}

// ---------- fallback: pure-f32 kernel (ws too small) -------------------------
__global__ __launch_bounds__(256) void zinb_edge_f32_kernel(
    const float* __restrict__ ufeats, const float* __restrict__ ifeats,
    const float* __restrict__ ge_factor, const float* __restrict__ sz_factor,
    const float* __restrict__ W_mean, const float* __restrict__ b_mean,
    const float* __restrict__ W_disp, const float* __restrict__ b_disp,
    const float* __restrict__ W_pi,   const float* __restrict__ b_pi,
    const int* __restrict__ src_idx, const int* __restrict__ dst_idx,
    float* __restrict__ out, int E)
{
    const int r = threadIdx.x & 7;
    const int slot = (blockIdx.x * blockDim.x + threadIdx.x) >> 3;
    const int n_slots = (gridDim.x * blockDim.x) >> 3;

    float4 wm[4], wd[4], wp[4];
    {
        const float4* wm4 = (const float4*)W_mean + r;
        const float4* wd4 = (const float4*)W_disp + r;
        const float4* wp4 = (const float4*)W_pi   + r;
#pragma unroll
        for (int c = 0; c < 4; ++c) { wm[c] = wm4[c*8]; wd[c] = wd4[c*8]; wp[c] = wp4[c*8]; }
    }
    const float bm = b_mean[0], bd = b_disp[0], bp = b_pi[0];

    for (int e = slot; e < E; e += n_slots) {
        const int s = src_idx[e];
        const int g = dst_idx[e];
        const float4* u4 = (const float4*)(ufeats + (size_t)s * 128) + r;
        const float4* v4 = (const float4*)(ifeats + (size_t)g * 128) + r;
        float am = 0.f, ad = 0.f, ap = 0.f;
#pragma unroll
        for (int c = 0; c < 4; ++c) {
            float4 u = u4[c*8]; float4 v = v4[c*8];
            float px = u.x*v.x, py = u.y*v.y, pz = u.z*v.z, pw = u.w*v.w;
            am = fmaf(px, wm[c].x, am); am = fmaf(py, wm[c].y, am);
            am = fmaf(pz, wm[c].z, am); am = fmaf(pw, wm[c].w, am);
            ad = fmaf(px, wd[c].x, ad); ad = fmaf(py, wd[c].y, ad);
            ad = fmaf(pz, wd[c].z, ad); ad = fmaf(pw, wd[c].w, ad);
            ap = fmaf(px, wp[c].x, ap); ap = fmaf(py, wp[c].y, ap);
            ap = fmaf(pz, wp[c].z, ap); ap = fmaf(pw, wp[c].w, ap);
        }
#pragma unroll
        for (int off = 1; off < 8; off <<= 1) {
            am += __shfl_xor(am, off); ad += __shfl_xor(ad, off); ap += __shfl_xor(ap, off);
        }
        if (r == 0) {
            const float gef = ge_factor[g];
            const float szf = sz_factor[s];
            const float mu_ = 1.f / (1.f + __expf(-(am + bm)));
            const float pi  = 1.f / (1.f + __expf(-(ap + bp)));
            const float xd  = gef * (ad + bd);
            const float sp  = fmaxf(xd, 0.f) + __logf(1.f + __expf(-fabsf(xd)));
            const float disp = fminf(fmaxf(sp, 1e-4f), 1e4f);
            const float mu = szf * fminf(fmaxf(__expf(gef * mu_) - 1.f, 1e-5f), 1e6f);
            out[e] = mu; out[(size_t)E + e] = disp; out[(size_t)2*E + e] = pi;
        }
    }
}

extern "C" void kernel_launch(void* const* d_in, const int* in_sizes, int n_in,
                              void* d_out, int out_size, void* d_ws, size_t ws_size,
                              hipStream_t stream) {
    const float* ufeats    = (const float*)d_in[0];
    const float* ifeats    = (const float*)d_in[1];
    const float* ge_factor = (const float*)d_in[2];
    const float* sz_factor = (const float*)d_in[3];
    const float* W_mean    = (const float*)d_in[4];
    const float* b_mean    = (const float*)d_in[5];
    const float* W_disp    = (const float*)d_in[6];
    const float* b_disp    = (const float*)d_in[7];
    const float* W_pi      = (const float*)d_in[8];
    const float* b_pi      = (const float*)d_in[9];
    const int*   src_idx   = (const int*)d_in[10];
    const int*   dst_idx   = (const int*)d_in[11];
    float* out = (float*)d_out;

    const int E       = in_sizes[10];
    const int n_cells = in_sizes[0] / 128;
    const int n_genes = in_sizes[1] / 128;

    const size_t u_elems = (size_t)n_cells * 128;
    const size_t i_elems = (size_t)n_genes * 128;
    const size_t ws_needed = (u_elems + i_elems) * sizeof(_Float16);

    if (ws_size >= ws_needed) {
        _Float16* uhalf = (_Float16*)d_ws;
        _Float16* ihalf = uhalf + u_elems;

        const int un4 = (int)(u_elems / 4);
        const int in4 = (int)(i_elems / 4);
        hipLaunchKernelGGL(cvt_f16_fused_kernel, dim3((un4 + in4 + 255) / 256), dim3(256), 0, stream,
                           (const float4*)ufeats, un4, (const float4*)ifeats, in4,
                           (uint2*)d_ws);

        hipLaunchKernelGGL(zinb_edge8p_kernel, dim3(2048), dim3(256), 0, stream,
                           uhalf, ihalf, ge_factor, sz_factor,
                           W_mean, b_mean, W_disp, b_disp, W_pi, b_pi,
                           src_idx, dst_idx, out, E);

        const int rem = E & 7;
        if (rem) {
            hipLaunchKernelGGL(zinb_tail_kernel, dim3(1), dim3(64), 0, stream,
                               ufeats, ifeats, ge_factor, sz_factor,
                               W_mean, b_mean, W_disp, b_disp, W_pi, b_pi,
                               src_idx, dst_idx, out, E, E - rem);
        }
    } else {
        hipLaunchKernelGGL(zinb_edge_f32_kernel, dim3(2048), dim3(256), 0, stream,
                           ufeats, ifeats, ge_factor, sz_factor,
                           W_mean, b_mean, W_disp, b_disp, W_pi, b_pi,
                           src_idx, dst_idx, out, E);
    }
}